// Round 1
// baseline (290.720 us; speedup 1.0000x reference)
//
#include <hip/hip_runtime.h>
#include <stdint.h>

#define NIMG     128
#define NPROP    2000
#define NGT      100
#define NALL     2100   // NPROP + NGT
#define NSORT    4096   // padded pow2 for bitonic
#define NSAMPLE  512
#define MAXPOS   128
#define NNEG     384
#define NTHREADS 256

#define SAMP_OFF  (NIMG * NSAMPLE * 4)            // 262144
#define MATCH_OFF (SAMP_OFF + NIMG * NSAMPLE)     // 327680

__global__ __launch_bounds__(NTHREADS) void sampler_kernel(
    const float* __restrict__ rois,    // (NIMG, NPROP, 4)
    const float* __restrict__ scores,  // (NIMG, NPROP, 1)
    const float* __restrict__ gts,     // (NIMG, NGT, 4)
    const float* __restrict__ rnd,     // (NIMG, NALL)
    float* __restrict__ out)           // [rois | samples | matches] flat
{
    __shared__ unsigned long long s_keys[NSORT];   // (rand_bits<<32)|pos
    __shared__ float s_gt[NGT * 4];
    __shared__ float s_ga[NGT];                    // gt areas
    __shared__ unsigned char s_mask[NALL];         // 0 / 2 / 3
    __shared__ short s_arg[NALL];                  // ious_argmax
    __shared__ int s_c0[NTHREADS], s_c1[NTHREADS], s_c2[NTHREADS];

    const int img = blockIdx.x;
    const int tid = threadIdx.x;

    // ---- load gt boxes, precompute areas ----
    for (int i = tid; i < NGT * 4; i += NTHREADS)
        s_gt[i] = gts[(size_t)img * NGT * 4 + i];
    __syncthreads();
    for (int g = tid; g < NGT; g += NTHREADS) {
        float w = fmaxf(s_gt[g * 4 + 2] - s_gt[g * 4 + 0], 0.0f);
        float h = fmaxf(s_gt[g * 4 + 3] - s_gt[g * 4 + 1], 0.0f);
        s_ga[g] = w * h;
    }
    __syncthreads();

    // ---- phase 1: mask, argmax, sort keys ----
    for (int i = tid; i < NALL; i += NTHREADS) {
        float x0, y0, x1, y1, sc;
        if (i < NPROP) {
            const float* p = rois + ((size_t)img * NPROP + i) * 4;
            x0 = p[0]; y0 = p[1]; x1 = p[2]; y1 = p[3];
            sc = scores[(size_t)img * NPROP + i];
        } else {
            int g = i - NPROP;
            x0 = s_gt[g * 4 + 0]; y0 = s_gt[g * 4 + 1];
            x1 = s_gt[g * 4 + 2]; y1 = s_gt[g * 4 + 3];
            sc = 1.0f;
        }
        float aw = fmaxf(x1 - x0, 0.0f);
        float ah = fmaxf(y1 - y0, 0.0f);
        float area_a = aw * ah;
        float best = -1.0f;
        int barg = 0;
        for (int g = 0; g < NGT; ++g) {
            float tlx = fmaxf(x0, s_gt[g * 4 + 0]);
            float tly = fmaxf(y0, s_gt[g * 4 + 1]);
            float brx = fminf(x1, s_gt[g * 4 + 2]);
            float bry = fminf(y1, s_gt[g * 4 + 3]);
            float iw = fmaxf(brx - tlx, 0.0f);
            float ih = fmaxf(bry - tly, 0.0f);
            float inter = iw * ih;
            float uni = area_a + s_ga[g] - inter;
            float iou = (uni > 0.0f) ? (inter / uni) : 0.0f;
            if (iou > best) { best = iou; barg = g; }   // first-max tie-break
        }
        unsigned char m = 2;
        if (sc < 0.0f) m = 0;
        if (best >= 0.5f) m = 3;   // overrides score<0, per reference order
        s_mask[i] = m;
        s_arg[i] = (short)barg;
        unsigned int bits = __float_as_uint(rnd[(size_t)img * NALL + i]);
        s_keys[i] = ((unsigned long long)bits << 32) | (unsigned int)i;
    }
    for (int i = NALL + tid; i < NSORT; i += NTHREADS)
        s_keys[i] = ~0ULL;
    __syncthreads();

    // ---- phase 2: bitonic sort ascending (stable via composite key) ----
    for (int k = 2; k <= NSORT; k <<= 1) {
        for (int j = k >> 1; j > 0; j >>= 1) {
            for (int i = tid; i < NSORT; i += NTHREADS) {
                int ixj = i ^ j;
                if (ixj > i) {
                    unsigned long long a = s_keys[i];
                    unsigned long long b = s_keys[ixj];
                    bool up = ((i & k) == 0);
                    if ((a > b) == up) { s_keys[i] = b; s_keys[ixj] = a; }
                }
            }
            __syncthreads();
        }
    }

    // ---- phase 3: top selection (priority 3 > 2 > 0) over [0, NALL) ----
    {
        const int C = 9;   // 256*9 = 2304 >= 2100
        int p0 = tid * C;
        int p1 = min(p0 + C, NALL);
        int c0 = 0, c1 = 0, c2 = 0;
        for (int p = p0; p < p1; ++p) {
            unsigned int orig = (unsigned int)(s_keys[p] & 0xFFFFFFFFu);
            unsigned char m = s_mask[orig];
            if (m == 3) ++c0; else if (m == 2) ++c1; else ++c2;
        }
        s_c0[tid] = c0; s_c1[tid] = c1; s_c2[tid] = c2;
        __syncthreads();
        for (int d = 1; d < NTHREADS; d <<= 1) {   // Hillis-Steele inclusive scan
            int a0 = (tid >= d) ? s_c0[tid - d] : 0;
            int a1 = (tid >= d) ? s_c1[tid - d] : 0;
            int a2 = (tid >= d) ? s_c2[tid - d] : 0;
            __syncthreads();
            s_c0[tid] += a0; s_c1[tid] += a1; s_c2[tid] += a2;
            __syncthreads();
        }
        int tot0 = s_c0[NTHREADS - 1];
        int tot1 = s_c1[NTHREADS - 1];
        int r0 = s_c0[tid] - c0;                 // exclusive prefixes
        int r1 = tot0 + s_c1[tid] - c1;
        int r2 = tot0 + tot1 + s_c2[tid] - c2;
        for (int p = p0; p < p1; ++p) {
            unsigned int orig = (unsigned int)(s_keys[p] & 0xFFFFFFFFu);
            unsigned char m = s_mask[orig];
            int slot; float samp;
            if (m == 3)      { slot = r0++; samp = 1.0f; }
            else if (m == 2) { slot = r1++; samp = -1.0f; }
            else             { slot = r2++; samp = 0.0f; }
            if (slot < MAXPOS) {
                float bx0, by0, bx1, by1;
                if (orig < NPROP) {
                    const float* p4 = rois + ((size_t)img * NPROP + orig) * 4;
                    bx0 = p4[0]; by0 = p4[1]; bx1 = p4[2]; by1 = p4[3];
                } else {
                    int g = orig - NPROP;
                    bx0 = s_gt[g * 4 + 0]; by0 = s_gt[g * 4 + 1];
                    bx1 = s_gt[g * 4 + 2]; by1 = s_gt[g * 4 + 3];
                }
                size_t rb = ((size_t)img * NSAMPLE + slot) * 4;
                out[rb + 0] = bx0; out[rb + 1] = by0;
                out[rb + 2] = bx1; out[rb + 3] = by1;
                out[SAMP_OFF  + (size_t)img * NSAMPLE + slot] = samp;
                out[MATCH_OFF + (size_t)img * NSAMPLE + slot] = (float)s_arg[orig];
            }
        }
        __syncthreads();
    }

    // ---- phase 4: bottom selection (priority 2 > 3 > 0) over [MAXPOS, NALL) ----
    {
        const int C = 8;   // 256*8 = 2048 >= 1972
        int p0 = MAXPOS + tid * C;
        int p1 = min(p0 + C, NALL);
        int c0 = 0, c1 = 0, c2 = 0;
        for (int p = p0; p < p1; ++p) {
            unsigned int orig = (unsigned int)(s_keys[p] & 0xFFFFFFFFu);
            unsigned char m = s_mask[orig];
            if (m == 2) ++c0; else if (m == 3) ++c1; else ++c2;
        }
        s_c0[tid] = c0; s_c1[tid] = c1; s_c2[tid] = c2;
        __syncthreads();
        for (int d = 1; d < NTHREADS; d <<= 1) {
            int a0 = (tid >= d) ? s_c0[tid - d] : 0;
            int a1 = (tid >= d) ? s_c1[tid - d] : 0;
            int a2 = (tid >= d) ? s_c2[tid - d] : 0;
            __syncthreads();
            s_c0[tid] += a0; s_c1[tid] += a1; s_c2[tid] += a2;
            __syncthreads();
        }
        int tot0 = s_c0[NTHREADS - 1];
        int tot1 = s_c1[NTHREADS - 1];
        int r0 = s_c0[tid] - c0;
        int r1 = tot0 + s_c1[tid] - c1;
        int r2 = tot0 + tot1 + s_c2[tid] - c2;
        for (int p = p0; p < p1; ++p) {
            unsigned int orig = (unsigned int)(s_keys[p] & 0xFFFFFFFFu);
            unsigned char m = s_mask[orig];
            int slot; float samp;
            if (m == 2)      { slot = r0++; samp = -1.0f; }   // mask2: 2->4, highest prio, sample -1
            else if (m == 3) { slot = r1++; samp = 1.0f; }
            else             { slot = r2++; samp = 0.0f; }
            if (slot < NNEG) {
                int oslot = MAXPOS + slot;
                float bx0, by0, bx1, by1;
                if (orig < NPROP) {
                    const float* p4 = rois + ((size_t)img * NPROP + orig) * 4;
                    bx0 = p4[0]; by0 = p4[1]; bx1 = p4[2]; by1 = p4[3];
                } else {
                    int g = orig - NPROP;
                    bx0 = s_gt[g * 4 + 0]; by0 = s_gt[g * 4 + 1];
                    bx1 = s_gt[g * 4 + 2]; by1 = s_gt[g * 4 + 3];
                }
                size_t rb = ((size_t)img * NSAMPLE + oslot) * 4;
                out[rb + 0] = bx0; out[rb + 1] = by0;
                out[rb + 2] = bx1; out[rb + 3] = by1;
                out[SAMP_OFF  + (size_t)img * NSAMPLE + oslot] = samp;
                out[MATCH_OFF + (size_t)img * NSAMPLE + oslot] = (float)s_arg[orig];
            }
        }
    }
}

extern "C" void kernel_launch(void* const* d_in, const int* in_sizes, int n_in,
                              void* d_out, int out_size, void* d_ws, size_t ws_size,
                              hipStream_t stream) {
    const float* rois   = (const float*)d_in[0];
    const float* scores = (const float*)d_in[1];
    const float* gts    = (const float*)d_in[2];
    const float* rnd    = (const float*)d_in[3];
    sampler_kernel<<<NIMG, NTHREADS, 0, stream>>>(rois, scores, gts, rnd, (float*)d_out);
}

// Round 2
// 147.698 us; speedup vs baseline: 1.9683x; 1.9683x over previous
//
#include <hip/hip_runtime.h>
#include <stdint.h>

#define NIMG     128
#define NPROP    2000
#define NGT      100
#define NALL     2100   // NPROP + NGT
#define NSORT    4096   // padded pow2 for bitonic
#define NSAMPLE  512
#define MAXPOS   128
#define NNEG     384
#define NTHREADS 1024   // 16 waves/block -> 4 waves/SIMD: latency hiding for LDS sort

#define SAMP_OFF  (NIMG * NSAMPLE * 4)            // 262144
#define MATCH_OFF (SAMP_OFF + NIMG * NSAMPLE)     // 327680

__global__ __launch_bounds__(NTHREADS) void sampler_kernel(
    const float* __restrict__ rois,    // (NIMG, NPROP, 4)
    const float* __restrict__ scores,  // (NIMG, NPROP, 1)
    const float* __restrict__ gts,     // (NIMG, NGT, 4)
    const float* __restrict__ rnd,     // (NIMG, NALL)
    float* __restrict__ out)           // [rois | samples | matches] flat
{
    __shared__ unsigned long long s_keys[NSORT];   // (rand_bits<<32)|pos
    __shared__ float s_gt[NGT * 4];
    __shared__ float s_ga[NGT];                    // gt areas
    __shared__ unsigned char s_mask[NALL];         // 0 / 2 / 3
    __shared__ short s_arg[NALL];                  // ious_argmax
    __shared__ int s_c0[NTHREADS], s_c1[NTHREADS], s_c2[NTHREADS];

    const int img = blockIdx.x;
    const int tid = threadIdx.x;

    // ---- load gt boxes, precompute areas ----
    for (int i = tid; i < NGT * 4; i += NTHREADS)
        s_gt[i] = gts[(size_t)img * NGT * 4 + i];
    __syncthreads();
    for (int g = tid; g < NGT; g += NTHREADS) {
        float w = fmaxf(s_gt[g * 4 + 2] - s_gt[g * 4 + 0], 0.0f);
        float h = fmaxf(s_gt[g * 4 + 3] - s_gt[g * 4 + 1], 0.0f);
        s_ga[g] = w * h;
    }
    __syncthreads();

    // ---- phase 1: mask, argmax, sort keys ----
    for (int i = tid; i < NALL; i += NTHREADS) {
        float x0, y0, x1, y1, sc;
        if (i < NPROP) {
            const float* p = rois + ((size_t)img * NPROP + i) * 4;
            x0 = p[0]; y0 = p[1]; x1 = p[2]; y1 = p[3];
            sc = scores[(size_t)img * NPROP + i];
        } else {
            int g = i - NPROP;
            x0 = s_gt[g * 4 + 0]; y0 = s_gt[g * 4 + 1];
            x1 = s_gt[g * 4 + 2]; y1 = s_gt[g * 4 + 3];
            sc = 1.0f;
        }
        float aw = fmaxf(x1 - x0, 0.0f);
        float ah = fmaxf(y1 - y0, 0.0f);
        float area_a = aw * ah;
        float best = -1.0f;
        int barg = 0;
        for (int g = 0; g < NGT; ++g) {
            float tlx = fmaxf(x0, s_gt[g * 4 + 0]);
            float tly = fmaxf(y0, s_gt[g * 4 + 1]);
            float brx = fminf(x1, s_gt[g * 4 + 2]);
            float bry = fminf(y1, s_gt[g * 4 + 3]);
            float iw = fmaxf(brx - tlx, 0.0f);
            float ih = fmaxf(bry - tly, 0.0f);
            float inter = iw * ih;
            float uni = area_a + s_ga[g] - inter;
            float iou = (uni > 0.0f) ? (inter / uni) : 0.0f;
            if (iou > best) { best = iou; barg = g; }   // first-max tie-break
        }
        unsigned char m = 2;
        if (sc < 0.0f) m = 0;
        if (best >= 0.5f) m = 3;   // overrides score<0, per reference order
        s_mask[i] = m;
        s_arg[i] = (short)barg;
        unsigned int bits = __float_as_uint(rnd[(size_t)img * NALL + i]);
        s_keys[i] = ((unsigned long long)bits << 32) | (unsigned int)i;
    }
    for (int i = NALL + tid; i < NSORT; i += NTHREADS)
        s_keys[i] = ~0ULL;
    __syncthreads();

    // ---- phase 2: bitonic sort ascending (stable via composite key) ----
    // pair-index form: thread t handles pair (i, i|j); no masked lanes.
    for (int k = 2; k <= NSORT; k <<= 1) {
        for (int j = k >> 1; j > 0; j >>= 1) {
            for (int t = tid; t < NSORT / 2; t += NTHREADS) {
                int low = t & (j - 1);
                int i   = ((t ^ low) << 1) | low;   // (t & ~(j-1))*2 + low
                int p   = i | j;
                unsigned long long a = s_keys[i];
                unsigned long long b = s_keys[p];
                bool up = ((i & k) == 0);
                if ((a > b) == up) { s_keys[i] = b; s_keys[p] = a; }
            }
            __syncthreads();
        }
    }

    // ---- phase 3: top selection (priority 3 > 2 > 0) over [0, NALL) ----
    {
        const int C = 3;   // 1024*3 = 3072 >= 2100
        int p0 = tid * C;
        int p1 = min(p0 + C, NALL);
        int c0 = 0, c1 = 0, c2 = 0;
        for (int p = p0; p < p1; ++p) {
            unsigned int orig = (unsigned int)(s_keys[p] & 0xFFFFFFFFu);
            unsigned char m = s_mask[orig];
            if (m == 3) ++c0; else if (m == 2) ++c1; else ++c2;
        }
        s_c0[tid] = c0; s_c1[tid] = c1; s_c2[tid] = c2;
        __syncthreads();
        for (int d = 1; d < NTHREADS; d <<= 1) {   // Hillis-Steele inclusive scan
            int a0 = (tid >= d) ? s_c0[tid - d] : 0;
            int a1 = (tid >= d) ? s_c1[tid - d] : 0;
            int a2 = (tid >= d) ? s_c2[tid - d] : 0;
            __syncthreads();
            s_c0[tid] += a0; s_c1[tid] += a1; s_c2[tid] += a2;
            __syncthreads();
        }
        int tot0 = s_c0[NTHREADS - 1];
        int tot1 = s_c1[NTHREADS - 1];
        int r0 = s_c0[tid] - c0;                 // exclusive prefixes
        int r1 = tot0 + s_c1[tid] - c1;
        int r2 = tot0 + tot1 + s_c2[tid] - c2;
        for (int p = p0; p < p1; ++p) {
            unsigned int orig = (unsigned int)(s_keys[p] & 0xFFFFFFFFu);
            unsigned char m = s_mask[orig];
            int slot; float samp;
            if (m == 3)      { slot = r0++; samp = 1.0f; }
            else if (m == 2) { slot = r1++; samp = -1.0f; }
            else             { slot = r2++; samp = 0.0f; }
            if (slot < MAXPOS) {
                float bx0, by0, bx1, by1;
                if (orig < NPROP) {
                    const float* p4 = rois + ((size_t)img * NPROP + orig) * 4;
                    bx0 = p4[0]; by0 = p4[1]; bx1 = p4[2]; by1 = p4[3];
                } else {
                    int g = orig - NPROP;
                    bx0 = s_gt[g * 4 + 0]; by0 = s_gt[g * 4 + 1];
                    bx1 = s_gt[g * 4 + 2]; by1 = s_gt[g * 4 + 3];
                }
                size_t rb = ((size_t)img * NSAMPLE + slot) * 4;
                out[rb + 0] = bx0; out[rb + 1] = by0;
                out[rb + 2] = bx1; out[rb + 3] = by1;
                out[SAMP_OFF  + (size_t)img * NSAMPLE + slot] = samp;
                out[MATCH_OFF + (size_t)img * NSAMPLE + slot] = (float)s_arg[orig];
            }
        }
        __syncthreads();
    }

    // ---- phase 4: bottom selection (priority 2 > 3 > 0) over [MAXPOS, NALL) ----
    {
        const int C = 2;   // 1024*2 = 2048 >= 1972
        int p0 = MAXPOS + tid * C;
        int p1 = min(p0 + C, NALL);
        int c0 = 0, c1 = 0, c2 = 0;
        for (int p = p0; p < p1; ++p) {
            unsigned int orig = (unsigned int)(s_keys[p] & 0xFFFFFFFFu);
            unsigned char m = s_mask[orig];
            if (m == 2) ++c0; else if (m == 3) ++c1; else ++c2;
        }
        s_c0[tid] = c0; s_c1[tid] = c1; s_c2[tid] = c2;
        __syncthreads();
        for (int d = 1; d < NTHREADS; d <<= 1) {
            int a0 = (tid >= d) ? s_c0[tid - d] : 0;
            int a1 = (tid >= d) ? s_c1[tid - d] : 0;
            int a2 = (tid >= d) ? s_c2[tid - d] : 0;
            __syncthreads();
            s_c0[tid] += a0; s_c1[tid] += a1; s_c2[tid] += a2;
            __syncthreads();
        }
        int tot0 = s_c0[NTHREADS - 1];
        int tot1 = s_c1[NTHREADS - 1];
        int r0 = s_c0[tid] - c0;
        int r1 = tot0 + s_c1[tid] - c1;
        int r2 = tot0 + tot1 + s_c2[tid] - c2;
        for (int p = p0; p < p1; ++p) {
            unsigned int orig = (unsigned int)(s_keys[p] & 0xFFFFFFFFu);
            unsigned char m = s_mask[orig];
            int slot; float samp;
            if (m == 2)      { slot = r0++; samp = -1.0f; }   // mask2: 2->4, highest prio, sample -1
            else if (m == 3) { slot = r1++; samp = 1.0f; }
            else             { slot = r2++; samp = 0.0f; }
            if (slot < NNEG) {
                int oslot = MAXPOS + slot;
                float bx0, by0, bx1, by1;
                if (orig < NPROP) {
                    const float* p4 = rois + ((size_t)img * NPROP + orig) * 4;
                    bx0 = p4[0]; by0 = p4[1]; bx1 = p4[2]; by1 = p4[3];
                } else {
                    int g = orig - NPROP;
                    bx0 = s_gt[g * 4 + 0]; by0 = s_gt[g * 4 + 1];
                    bx1 = s_gt[g * 4 + 2]; by1 = s_gt[g * 4 + 3];
                }
                size_t rb = ((size_t)img * NSAMPLE + oslot) * 4;
                out[rb + 0] = bx0; out[rb + 1] = by0;
                out[rb + 2] = bx1; out[rb + 3] = by1;
                out[SAMP_OFF  + (size_t)img * NSAMPLE + oslot] = samp;
                out[MATCH_OFF + (size_t)img * NSAMPLE + oslot] = (float)s_arg[orig];
            }
        }
    }
}

extern "C" void kernel_launch(void* const* d_in, const int* in_sizes, int n_in,
                              void* d_out, int out_size, void* d_ws, size_t ws_size,
                              hipStream_t stream) {
    const float* rois   = (const float*)d_in[0];
    const float* scores = (const float*)d_in[1];
    const float* gts    = (const float*)d_in[2];
    const float* rnd    = (const float*)d_in[3];
    sampler_kernel<<<NIMG, NTHREADS, 0, stream>>>(rois, scores, gts, rnd, (float*)d_out);
}